// Round 5
// baseline (110.458 us; speedup 1.0000x reference)
//
#include <hip/hip_runtime.h>

// PrRoIPool2D forward, MI355X. B=8, C=256, H=W=48, R=300, 7x7 bins, scale=1/16.
// R15: loop inversion — stage feature tile ONCE, sweep all ROIs over it.
//  - item = (image b, channel pair). 1024 blocks x 128 threads; block's 2 waves
//    cooperatively stage full 48x48x2ch tile (18.4 KB) into LDS once (coalesced,
//    zero overfetch), ONE __syncthreads, then each wave processes its half of
//    image b's ROI list (~19 ROIs) barrier-free out of LDS.
//  - global-load latency paid once per ~19 ROIs (R14: once per ROI, 9600x).
//    FETCH 48 MB -> ~19 MB unique. prm rows L1-hot across ROIs.
//  - ROI->image lists built deterministically in prep block 75 (no atomics;
//    list order has no numeric effect: each (r,bin,c) is independent).
//  - patch float2-interleaved, XOR swizzle off^((j&7)<<2) (injective: mask
//    bits 2..4 stay within the 32-float bucket; float2 alignment preserved).
//  - 8 waves/CU (2/SIMD) for mutual latency hiding; rs per-wave, same-wave
//    DS ordering makes PA(k+1)-vs-PB(k) hazard safe; fences kept anyway.
// Numerics: identical tap order/forms as R10-R14 (x taps ii=0..5, y taps
// jj=0..5, then *inv_area) -> absmax unchanged.

#define PH 7
#define PW 7
#define NBINS 49
#define SCALE 0.0625f
#define CH 256
#define FH 48
#define FW 48
#define RNUM 300
#define PRM 112                  // param stride per roi (floats)
#define PRMF (RNUM * PRM)        // 33600 floats
#define LISTCAP 304              // per-image list capacity (ints)
#define RSF 332                  // 7*23*2 = 322, padded
// prm layout: [0+ph*6]: wy[7][6] | [42+pw*6]: wx[7][6] | [84+ph]: bj (int)
// [91+pw]: bi (int) | [98]: inv_area | [99]: b | [100]: J0 | [101]: I0
// [102]: JROWS | [103]: NI4   (ints stored as float bit patterns)
// then at float offset PRMF: int lst[8][LISTCAP]; int cnt[8]

__device__ __forceinline__ float hat_int(float x, float g) {
    float t = x - (g - 1.0f);
    if (t <= 0.0f) return 0.0f;
    if (t <= 1.0f) return 0.5f * t * t;
    if (t <= 2.0f) { float u = 2.0f - t; return 1.0f - 0.5f * u * u; }
    return 1.0f;
}

// ---- prep: per-roi params (blocks 0..74) + per-image ROI lists (block 75) ----
__global__ __launch_bounds__(256)
void prroi_prep(const float* __restrict__ rois, float* __restrict__ prm) {
    if (blockIdx.x == 75) {                      // deterministic list build
        __shared__ int lb[RNUM];
        int* lst = (int*)(prm + PRMF);
        int* cnt = lst + 8 * LISTCAP;
        const int tid = threadIdx.x;
        for (int u = tid; u < RNUM; u += 256) lb[u] = (int)rois[5 * u];
        __syncthreads();
        for (int u = tid; u < RNUM; u += 256) {
            const int bu = lb[u];
            int pos = 0;
            for (int r2 = 0; r2 < u; ++r2) pos += (lb[r2] == bu) ? 1 : 0;
            lst[bu * LISTCAP + pos] = u;
        }
        if (tid < 8) {
            int c = 0;
            for (int r2 = 0; r2 < RNUM; ++r2) c += (lb[r2] == tid) ? 1 : 0;
            cnt[tid] = c;
        }
        return;
    }

    const int r = blockIdx.x * 4 + (threadIdx.x >> 6);
    const int t = threadIdx.x & 63;
    if (r >= RNUM || t >= 15) return;

    const float* roi = rois + r * 5;
    const int   b  = (int)roi[0];
    const float x1 = roi[1] * SCALE, y1 = roi[2] * SCALE;
    const float x2 = roi[3] * SCALE, y2 = roi[4] * SCALE;
    const float roi_w = fmaxf(x2 - x1, 0.0f), roi_h = fmaxf(y2 - y1, 0.0f);
    const float bin_w = roi_w / (float)PW, bin_h = roi_h / (float)PH;
    const float area = bin_w * bin_h;
    const float inv_area = (area > 0.0f) ? (1.0f / area) : 0.0f;

    const float ylo = fminf(y1, y2), yhi = fmaxf(y1, y2);
    const float xlo = fminf(x1, x2), xhi = fmaxf(x1, x2);
    const int j1 = min(FH - 1, (int)floorf(yhi) + 1);
    const int i1 = min(FW - 1, (int)floorf(xhi) + 1);
    const int J0 = min(max(0, (int)floorf(ylo) - 1), FH - 6);
    const int I0 = min(max(0, (int)floorf(xlo) - 1) & ~3, FW - 8);
    const int JROWS = min(FH - J0, max(j1 - J0 + 1, 6));        // 6..23
    int NI4 = min(((i1 - I0) >> 2) + 1, (FW - I0) >> 2);
    NI4 = max(NI4, 2);                                           // 2..7

    float* p = prm + (size_t)r * PRM;
    if (t < PH) {
        const int ph = t;
        const float ya = y1 + ph * bin_h, yb = ya + bin_h;
        const int base = min(max((int)floorf(ya) - 1, J0), J0 + JROWS - 6);
        p[84 + ph] = __int_as_float(base - J0);
#pragma unroll
        for (int k = 0; k < 6; ++k) {
            const float g = (float)(base + k);
            p[ph * 6 + k] = hat_int(yb, g) - hat_int(ya, g);
        }
    } else if (t < PH + PW) {
        const int pw = t - PH;
        const float xa = x1 + pw * bin_w, xb = xa + bin_w;
        const int base = min(max((int)floorf(xa) - 1, I0), I0 + 4 * NI4 - 6);
        p[91 + pw] = __int_as_float(base - I0);
#pragma unroll
        for (int k = 0; k < 6; ++k) {
            const float g = (float)(base + k);
            p[42 + pw * 6 + k] = hat_int(xb, g) - hat_int(xa, g);
        }
    } else {                                                     // t == 14
        p[98]  = inv_area;
        p[99]  = __int_as_float(b);
        p[100] = __int_as_float(J0);
        p[101] = __int_as_float(I0);
        p[102] = __int_as_float(JROWS);
        p[103] = __int_as_float(NI4);
    }
}

// ---- main: block = (b, channel-quad); wave = (b, channel-pair) x half-ROIs ----
__global__ __launch_bounds__(128, 2)
void prroi_main(const float* __restrict__ feat,
                const float* __restrict__ prm,
                float* __restrict__ out) {
    const int bid = blockIdx.x;                 // 0..1023
    const int b   = bid >> 7;                   // image 0..7
    const int c2  = bid & 127;                  // channel pair 0..127
    const int c0  = c2 * 2;
    const int tid = threadIdx.x;                // 0..127
    const int wv  = tid >> 6, lane = tid & 63;

    __shared__ float patch[FH * FW * 2];        // float2-interleaved, 18432 B
    __shared__ float rsw[2][RSF];               // per-wave row-sums, 2656 B

    // ---- stage full tile once: 576 float4 units per channel, coalesced ----
    const float* fb = feat + (size_t)(b * CH + c0) * (FH * FW);
    for (int u = tid; u < (FH * FW / 4); u += 128) {   // u*4 = j*48 + 4*i4
        const int j  = u / 12;                          // 12 float4 per row
        const float4 a = *(const float4*)(fb + u * 4);              // ch c0
        const float4 c = *(const float4*)(fb + FH * FW + u * 4);    // ch c0+1
        const int o0 = u * 8;                           // = (j*48 + 4*i4)*2
        const int sw = (j & 7) << 2;
        *(float2*)&patch[(o0 + 0) ^ sw] = make_float2(a.x, c.x);
        *(float2*)&patch[(o0 + 2) ^ sw] = make_float2(a.y, c.y);
        *(float2*)&patch[(o0 + 4) ^ sw] = make_float2(a.z, c.z);
        *(float2*)&patch[(o0 + 6) ^ sw] = make_float2(a.w, c.w);
    }
    __syncthreads();                            // the ONLY barrier

    const int* lst = (const int*)(prm + PRMF);
    const int cnt  = lst[8 * LISTCAP + b];      // uniform -> s_load
    float* rsme = rsw[wv];

    const int  pwA  = lane >> 3, jsl = lane & 7;
    const bool actA = lane < 56;
    const bool actB = lane < NBINS;
    int phB = 0, pwB = 0;
    if (actB) { phB = lane / 7; pwB = lane - phB * 7; }

    for (int k = wv; k < cnt; k += 2) {         // wave-private ROI sweep
        const int r = lst[b * LISTCAP + k];     // uniform
        const float* p = prm + (size_t)r * PRM;
        const float ia = p[98];
        const int J0    = __float_as_int(p[100]);
        const int I0    = __float_as_int(p[101]);
        const int JROWS = __float_as_int(p[102]);

        float wx[6]; int biA = 0;
        if (actA) {
            biA = I0 + __float_as_int(p[91 + pwA]);   // absolute first x-tap
#pragma unroll
            for (int t6 = 0; t6 < 6; ++t6) wx[t6] = p[42 + pwA * 6 + t6];
        }
        float wy[6]; int bj = 0;
        if (actB) {
            bj = __float_as_int(p[84 + phB]);
#pragma unroll
            for (int t6 = 0; t6 < 6; ++t6) wy[t6] = p[phB * 6 + t6];
        }

        // PA: rs[pw][jr][c2] = sum_i wx * patch  (rows J0..J0+JROWS-1)
        if (actA) {
            for (int jr = jsl; jr < JROWS; jr += 8) {
                const int j  = J0 + jr;
                const int o0 = (j * FW + biA) * 2;
                const int sw = (j & 7) << 2;
                float ax = 0.0f, ay = 0.0f;
#pragma unroll
                for (int ii = 0; ii < 6; ++ii) {
                    const float2 v = *(const float2*)&patch[(o0 + 2 * ii) ^ sw];
                    ax += wx[ii] * v.x; ay += wx[ii] * v.y;
                }
                *(float2*)&rsme[(pwA * 23 + jr) * 2] = make_float2(ax, ay);
            }
        }
        asm volatile("s_waitcnt lgkmcnt(0)" ::: "memory");

        // PB: out[bin][c2] = sum_j wy * rs
        if (actB) {
            float ax = 0.0f, ay = 0.0f;
#pragma unroll
            for (int jj = 0; jj < 6; ++jj) {
                const float2 v = *(const float2*)&rsme[(pwB * 23 + bj + jj) * 2];
                ax += wy[jj] * v.x; ay += wy[jj] * v.y;
            }
            float* o = out + ((size_t)r * CH + c0) * NBINS + lane;
            o[0]     = ax * ia;                 // channel c0
            o[NBINS] = ay * ia;                 // channel c0+1
        }
        asm volatile("s_waitcnt lgkmcnt(0)" ::: "memory");
    }
}

extern "C" void kernel_launch(void* const* d_in, const int* in_sizes, int n_in,
                              void* d_out, int out_size, void* d_ws, size_t ws_size,
                              hipStream_t stream) {
    const float* feat = (const float*)d_in[0];
    const float* rois = (const float*)d_in[1];
    float* out = (float*)d_out;
    float* prm = (float*)d_ws;   // 144.2 KB used (poison is sunk cost)

    prroi_prep<<<76, 256, 0, stream>>>(rois, prm);
    prroi_main<<<1024, 128, 0, stream>>>(feat, prm, out);
}

// Round 6
// 87.148 us; speedup vs baseline: 1.2675x; 1.2675x over previous
//
#include <hip/hip_runtime.h>

// PrRoIPool2D forward, MI355X. B=8, C=256, H=W=48, R=300, 7x7 bins, scale=1/16.
// R16: R14 wave-per-item structure (best measured) + serial-chain cuts.
//  - R15 post-mortem: fewer/longer waves regressed 2x -> keep 24 independent
//    waves/CU, shorten each item's dependent chain instead.
//  - prm repacked to 8-float rows: wy[ph][8] (bj in slot 6), wx[pw][8] (bi in
//    slot 6), float4+float2 header -> 6 vector param loads/lane (was ~15).
//  - NO XOR swizzle (R12: conflicts off critical path): linear patch/rs ->
//    immediate-offset float2/float4 LDS reads, address VALU deleted.
//  - 2 items per wave, SAME r (wave = (r, c4): channels c0..c3 as two
//    2-channel items): params loaded once; all 12 staging float4 issued up
//    front so item-B HBM latency hides under item-A compute. Single patch
//    buffer reuse is safe: PA(A) read values consumed by FMAs (compiler
//    lgkmcnt) before patch-B writes; explicit fences at phase edges.
// Numerics: identical weight values, tap order (x ii=0..5, y jj=0..5, then
// *inv_area), sequential accumulation -> absmax unchanged.

#define PH 7
#define PW 7
#define NBINS 49
#define SCALE 0.0625f
#define CH 256
#define FH 48
#define FW 48
#define RNUM 300
#define PRM 128                  // param stride per roi (floats), 512 B
#define PATCHF (23 * 56)         // [j<23][i<28][c2] linear, 5152 B
#define RSF 328                  // 7*23*2 = 322, padded
// prm layout: [ph*8+k]: wy (k=0..5), [ph*8+6]: bj rel J0 | [56+pw*8+k]: wx,
// [56+pw*8+6]: bi rel I0 | [112..115]: ia, b, J0, I0 | [116,117]: JROWS, NI4

__device__ __forceinline__ float hat_int(float x, float g) {
    float t = x - (g - 1.0f);
    if (t <= 0.0f) return 0.0f;
    if (t <= 1.0f) return 0.5f * t * t;
    if (t <= 2.0f) { float u = 2.0f - t; return 1.0f - 0.5f * u * u; }
    return 1.0f;
}

// ---- prep: per-roi windows/weights/bounds, packed layout ----
__global__ __launch_bounds__(256)
void prroi_prep(const float* __restrict__ rois, float* __restrict__ prm) {
    const int r = blockIdx.x * 4 + (threadIdx.x >> 6);
    const int t = threadIdx.x & 63;
    if (r >= RNUM || t >= 15) return;

    const float* roi = rois + r * 5;
    const int   b  = (int)roi[0];
    const float x1 = roi[1] * SCALE, y1 = roi[2] * SCALE;
    const float x2 = roi[3] * SCALE, y2 = roi[4] * SCALE;
    const float roi_w = fmaxf(x2 - x1, 0.0f), roi_h = fmaxf(y2 - y1, 0.0f);
    const float bin_w = roi_w / (float)PW, bin_h = roi_h / (float)PH;
    const float area = bin_w * bin_h;
    const float inv_area = (area > 0.0f) ? (1.0f / area) : 0.0f;

    const float ylo = fminf(y1, y2), yhi = fmaxf(y1, y2);
    const float xlo = fminf(x1, x2), xhi = fmaxf(x1, x2);
    const int j1 = min(FH - 1, (int)floorf(yhi) + 1);
    const int i1 = min(FW - 1, (int)floorf(xhi) + 1);
    const int J0 = min(max(0, (int)floorf(ylo) - 1), FH - 6);
    const int I0 = min(max(0, (int)floorf(xlo) - 1) & ~3, FW - 8);
    const int JROWS = min(FH - J0, max(j1 - J0 + 1, 6));        // 6..23
    int NI4 = min(((i1 - I0) >> 2) + 1, (FW - I0) >> 2);
    NI4 = max(NI4, 2);                                           // 2..7

    float* p = prm + (size_t)r * PRM;
    if (t < PH) {
        const int ph = t;
        const float ya = y1 + ph * bin_h, yb = ya + bin_h;
        const int base = min(max((int)floorf(ya) - 1, J0), J0 + JROWS - 6);
        p[ph * 8 + 6] = __int_as_float(base - J0);
#pragma unroll
        for (int k = 0; k < 6; ++k) {
            const float g = (float)(base + k);
            p[ph * 8 + k] = hat_int(yb, g) - hat_int(ya, g);
        }
    } else if (t < PH + PW) {
        const int pw = t - PH;
        const float xa = x1 + pw * bin_w, xb = xa + bin_w;
        const int base = min(max((int)floorf(xa) - 1, I0), I0 + 4 * NI4 - 6);
        p[56 + pw * 8 + 6] = __int_as_float(base - I0);
#pragma unroll
        for (int k = 0; k < 6; ++k) {
            const float g = (float)(base + k);
            p[56 + pw * 8 + k] = hat_int(xb, g) - hat_int(xa, g);
        }
    } else {                                                     // t == 14
        p[112] = inv_area;
        p[113] = __int_as_float(b);
        p[114] = __int_as_float(J0);
        p[115] = __int_as_float(I0);
        p[116] = __int_as_float(JROWS);
        p[117] = __int_as_float(NI4);
    }
}

// ---- main: wave = (r, c4-group); two 2-channel items per wave ----
__global__ __launch_bounds__(256, 6)
void prroi_main(const float* __restrict__ feat,
                const float* __restrict__ prm,
                float* __restrict__ out) {
    const int wv   = threadIdx.x >> 6;          // wave 0..3
    const int lane = threadIdx.x & 63;
    const int r    = blockIdx.y;                // 0..299
    const int c4   = blockIdx.x * 4 + wv;       // 0..63
    const int c0   = c4 * 4;

    __shared__ float lds[4][PATCHF + RSF];      // 25920 B -> 6 blocks/CU
    float* patch = lds[wv];
    float* rsw   = lds[wv] + PATCHF;

    const float* p = prm + (size_t)r * PRM;
    const float4 h0 = *(const float4*)(p + 112);
    const float2 h1 = *(const float2*)(p + 116);
    const float ia  = h0.x;
    const int b     = __float_as_int(h0.y);
    const int J0    = __float_as_int(h0.z);
    const int I0    = __float_as_int(h0.w);
    const int JROWS = __float_as_int(h1.x);
    const int NI4   = __float_as_int(h1.y);

    // ---- roles + packed param loads (2 x b128 per role) ----
    const int  pwA = lane >> 3, jsl = lane & 7;
    const bool actA = lane < 56;
    float wx0 = 0, wx1 = 0, wx2 = 0, wx3 = 0, wx4 = 0, wx5 = 0;
    int biA = 0;
    if (actA) {
        const float4 wa = *(const float4*)(p + 56 + pwA * 8);
        const float4 wb = *(const float4*)(p + 56 + pwA * 8 + 4);
        wx0 = wa.x; wx1 = wa.y; wx2 = wa.z; wx3 = wa.w;
        wx4 = wb.x; wx5 = wb.y; biA = __float_as_int(wb.z);
    }
    const bool actB = lane < NBINS;
    float wy0 = 0, wy1 = 0, wy2 = 0, wy3 = 0, wy4 = 0, wy5 = 0;
    int pwB = 0, bjB = 0;
    if (actB) {
        const int ph = lane / 7;
        pwB = lane - ph * 7;
        const float4 ua = *(const float4*)(p + ph * 8);
        const float4 ub = *(const float4*)(p + ph * 8 + 4);
        wy0 = ua.x; wy1 = ua.y; wy2 = ua.z; wy3 = ua.w;
        wy4 = ub.x; wy5 = ub.y; bjB = __float_as_int(ub.z);
    }

    // ---- stage loads for BOTH items (channels c0..c3), issued up front ----
    const int NU = JROWS << 3;                  // (j, i4) units
    const float* fb = feat + (size_t)(b * CH + c0) * (FH * FW);
    const float* srcp[3];
    bool act_[3]; int dst_[3];
    float4 pa0[3], pa1[3], pb0[3], pb1[3];
#pragma unroll
    for (int s = 0; s < 3; ++s) {
        const int u  = lane + (s << 6);
        const int j  = u >> 3, i4 = u & 7;
        const bool a = (u < NU) && (i4 < NI4);
        act_[s] = a;
        dst_[s] = j * 56 + 8 * i4;
        srcp[s] = fb + (size_t)(J0 + j) * FW + I0 + 4 * i4;
        if (a) {                                 // item A: channels c0, c0+1
            pa0[s] = *(const float4*)(srcp[s]);
            pa1[s] = *(const float4*)(srcp[s] + FH * FW);
        }
    }
#pragma unroll
    for (int s = 0; s < 3; ++s) {
        if (act_[s]) {                           // item B: channels c0+2, c0+3
            pb0[s] = *(const float4*)(srcp[s] + 2 * FH * FW);
            pb1[s] = *(const float4*)(srcp[s] + 3 * FH * FW);
        }
    }

    // ---- item A: write patch, PA, PB ----
#pragma unroll
    for (int s = 0; s < 3; ++s) {
        if (act_[s]) {
            float* d = patch + dst_[s];
            *(float4*)(d + 0) = make_float4(pa0[s].x, pa1[s].x, pa0[s].y, pa1[s].y);
            *(float4*)(d + 4) = make_float4(pa0[s].z, pa1[s].z, pa0[s].w, pa1[s].w);
        }
    }
    asm volatile("s_waitcnt lgkmcnt(0)" ::: "memory");

#pragma unroll 1
    for (int it = 0; it < 2; ++it) {
        // PA: rs[pw][jr][c2] = sum_i wx * patch (linear, immediate offsets)
        if (actA) {
            for (int jr = jsl; jr < JROWS; jr += 8) {
                const float* row = patch + jr * 56 + 2 * biA;
                const float2 v0 = *(const float2*)(row + 0);
                const float2 v1 = *(const float2*)(row + 2);
                const float2 v2 = *(const float2*)(row + 4);
                const float2 v3 = *(const float2*)(row + 6);
                const float2 v4 = *(const float2*)(row + 8);
                const float2 v5 = *(const float2*)(row + 10);
                float ax = 0.0f, ay = 0.0f;
                ax += wx0 * v0.x; ay += wx0 * v0.y;
                ax += wx1 * v1.x; ay += wx1 * v1.y;
                ax += wx2 * v2.x; ay += wx2 * v2.y;
                ax += wx3 * v3.x; ay += wx3 * v3.y;
                ax += wx4 * v4.x; ay += wx4 * v4.y;
                ax += wx5 * v5.x; ay += wx5 * v5.y;
                *(float2*)&rsw[(pwA * 23 + jr) * 2] = make_float2(ax, ay);
            }
        }
        asm volatile("s_waitcnt lgkmcnt(0)" ::: "memory");

        // PB: out[bin][c2] = sum_j wy * rs
        if (actB) {
            const float* rb = rsw + (pwB * 23 + bjB) * 2;
            const float2 u0 = *(const float2*)(rb + 0);
            const float2 u1 = *(const float2*)(rb + 2);
            const float2 u2 = *(const float2*)(rb + 4);
            const float2 u3 = *(const float2*)(rb + 6);
            const float2 u4 = *(const float2*)(rb + 8);
            const float2 u5 = *(const float2*)(rb + 10);
            float ax = 0.0f, ay = 0.0f;
            ax += wy0 * u0.x; ay += wy0 * u0.y;
            ax += wy1 * u1.x; ay += wy1 * u1.y;
            ax += wy2 * u2.x; ay += wy2 * u2.y;
            ax += wy3 * u3.x; ay += wy3 * u3.y;
            ax += wy4 * u4.x; ay += wy4 * u4.y;
            ax += wy5 * u5.x; ay += wy5 * u5.y;
            float* o = out + ((size_t)r * CH + c0 + 2 * it) * NBINS + lane;
            o[0]     = ax * ia;                 // channel c0+2*it
            o[NBINS] = ay * ia;                 // channel c0+2*it+1
        }

        // stage item B's patch (loads long in flight); safe vs PA(A) reads:
        // their values were consumed by FMAs above (compiler-enforced waits)
        if (it == 0) {
            asm volatile("s_waitcnt lgkmcnt(0)" ::: "memory");
#pragma unroll
            for (int s = 0; s < 3; ++s) {
                if (act_[s]) {
                    float* d = patch + dst_[s];
                    *(float4*)(d + 0) = make_float4(pb0[s].x, pb1[s].x, pb0[s].y, pb1[s].y);
                    *(float4*)(d + 4) = make_float4(pb0[s].z, pb1[s].z, pb0[s].w, pb1[s].w);
                }
            }
            asm volatile("s_waitcnt lgkmcnt(0)" ::: "memory");
        }
    }
}

extern "C" void kernel_launch(void* const* d_in, const int* in_sizes, int n_in,
                              void* d_out, int out_size, void* d_ws, size_t ws_size,
                              hipStream_t stream) {
    const float* feat = (const float*)d_in[0];
    const float* rois = (const float*)d_in[1];
    float* out = (float*)d_out;
    float* prm = (float*)d_ws;   // 300 * 128 * 4 = 153.6 KB (poison is sunk cost)

    prroi_prep<<<(RNUM + 3) / 4, 256, 0, stream>>>(rois, prm);
    prroi_main<<<dim3(16, RNUM), 256, 0, stream>>>(feat, prm, out);
}